// Round 1
// baseline (230.940 us; speedup 1.0000x reference)
//
#include <hip/hip_runtime.h>
#include <hip/hip_bf16.h>

typedef __attribute__((ext_vector_type(8))) short bf16x8;
typedef __attribute__((ext_vector_type(4))) float f32x4;

#define B_SZ   1024
#define T_SZ   128
#define L_SZ   256
#define F_SZ   784
#define M_TOT  (B_SZ * T_SZ)            // 131072
#define BM     128
#define BK     32
#define KSTEPS ((F_SZ + BK - 1) / BK)   // 25 (last step padded with zeros)

__device__ __forceinline__ unsigned short f2bf(float f) {
    __hip_bfloat16 h = __float2bfloat16(f);   // RTNE
    return *reinterpret_cast<unsigned short*>(&h);
}

__global__ __launch_bounds__(512) void dn_fused(
    const float* __restrict__ x, const float* __restrict__ W,
    const float* __restrict__ bias, const float* __restrict__ contrib,
    float* __restrict__ out)
{
    // kgroup-major LDS: frag read = 16 consecutive lanes x 16B contiguous
    __shared__ bf16x8 As[4][BM];     // [kgrp][row]   bf16 x tile
    __shared__ bf16x8 Bs[4][L_SZ];   // [kgrp][leaf]  bf16 W tile

    const int tid    = threadIdx.x;
    const int lane   = tid & 63;
    const int wid    = tid >> 6;       // 0..7
    const int waveM  = wid >> 2;       // 0..1
    const int waveN  = wid & 3;        // 0..3
    const int blkRow = blockIdx.x * BM;

    // staging assignments
    const int ar = tid >> 2;           // x row within tile, 0..127 (4 thr/row)
    const int ak = (tid & 3) * 8;      // x k offset: 0,8,16,24
    const int wr = tid >> 1;           // W row (leaf), 0..255 (2 thr/row)
    const int wk = (tid & 1) * 16;     // W k offset: 0,16

    const int laneRow = lane & 15;
    const int kgrp    = lane >> 4;

    f32x4 acc[4][4];
    #pragma unroll
    for (int i = 0; i < 4; ++i)
        #pragma unroll
        for (int j = 0; j < 4; ++j)
            acc[i][j] = (f32x4){0.f, 0.f, 0.f, 0.f};

    const float* xrow = x + (size_t)(blkRow + ar) * F_SZ;
    const float* wrow = W + (size_t)wr * F_SZ;

    const f32x4 zf = {0.f, 0.f, 0.f, 0.f};

    // prologue: load K-tile 0 into registers (k=0..31, always in-bounds)
    f32x4 xa0 = *reinterpret_cast<const f32x4*>(xrow + ak);
    f32x4 xa1 = *reinterpret_cast<const f32x4*>(xrow + ak + 4);
    f32x4 wa0 = *reinterpret_cast<const f32x4*>(wrow + wk);
    f32x4 wa1 = *reinterpret_cast<const f32x4*>(wrow + wk + 4);
    f32x4 wa2 = *reinterpret_cast<const f32x4*>(wrow + wk + 8);
    f32x4 wa3 = *reinterpret_cast<const f32x4*>(wrow + wk + 12);

    for (int ks = 0; ks < KSTEPS; ++ks) {
        // convert staged regs f32 -> bf16, write LDS
        bf16x8 av, wv0, wv1;
        #pragma unroll
        for (int j = 0; j < 4; ++j) {
            av[j]      = (short)f2bf(xa0[j]);
            av[4 + j]  = (short)f2bf(xa1[j]);
            wv0[j]     = (short)f2bf(wa0[j]);
            wv0[4 + j] = (short)f2bf(wa1[j]);
            wv1[j]     = (short)f2bf(wa2[j]);
            wv1[4 + j] = (short)f2bf(wa3[j]);
        }
        As[ak >> 3][ar] = av;
        Bs[wk >> 3][wr] = wv0;
        Bs[(wk >> 3) + 1][wr] = wv1;
        __syncthreads();

        // prefetch next K-tile into registers (latency hides under MFMA)
        if (ks + 1 < KSTEPS) {
            const int kb = (ks + 1) * BK;
            if (kb + ak < F_SZ) {   // spans never straddle 784 (784%8==0)
                xa0 = *reinterpret_cast<const f32x4*>(xrow + kb + ak);
                xa1 = *reinterpret_cast<const f32x4*>(xrow + kb + ak + 4);
            } else { xa0 = zf; xa1 = zf; }
            if (kb + wk < F_SZ) {   // 784%16==0
                wa0 = *reinterpret_cast<const f32x4*>(wrow + kb + wk);
                wa1 = *reinterpret_cast<const f32x4*>(wrow + kb + wk + 4);
                wa2 = *reinterpret_cast<const f32x4*>(wrow + kb + wk + 8);
                wa3 = *reinterpret_cast<const f32x4*>(wrow + kb + wk + 12);
            } else { wa0 = zf; wa1 = zf; wa2 = zf; wa3 = zf; }
        }

        // fragments + MFMA
        bf16x8 af[4], bfv[4];
        #pragma unroll
        for (int mi = 0; mi < 4; ++mi)
            af[mi] = As[kgrp][waveM * 64 + mi * 16 + laneRow];
        #pragma unroll
        for (int ni = 0; ni < 4; ++ni)
            bfv[ni] = Bs[kgrp][waveN * 64 + ni * 16 + laneRow];
        #pragma unroll
        for (int mi = 0; mi < 4; ++mi)
            #pragma unroll
            for (int ni = 0; ni < 4; ++ni)
                acc[mi][ni] = __builtin_amdgcn_mfma_f32_16x16x32_bf16(
                    af[mi], bfv[ni], acc[mi][ni], 0, 0, 0);
        __syncthreads();
    }

    // fused epilogue: sp = clip(acc + b, -1, 1); gini = 1 + 2*s*(1-s), s = sigmoid(sp*dk)
    const size_t GOFF  = (size_t)M_TOT * L_SZ;
    const int    rbase = waveM * 64 + (lane >> 4) * 4;
    const int    cbase = waveN * 64 + laneRow;
    #pragma unroll
    for (int ni = 0; ni < 4; ++ni) {
        const int col = cbase + ni * 16;
        const float bb = bias[col];
        #pragma unroll
        for (int mi = 0; mi < 4; ++mi) {
            #pragma unroll
            for (int r = 0; r < 4; ++r) {
                const int m = blkRow + rbase + mi * 16 + r;
                const int t = m & (T_SZ - 1);
                float v  = acc[mi][ni][r] + bb;
                float sp = fminf(fmaxf(v, -1.f), 1.f);
                const float* cp = contrib + (size_t)(t * L_SZ + col) * 2;
                const float d  = sp * (cp[0] - cp[1]);
                const float ed = __expf(d);
                const float s  = ed / (1.f + ed);
                const float g  = fmaf(2.f * s, 1.f - s, 1.f);
                const size_t o = (size_t)m * L_SZ + col;
                out[o]        = sp;
                out[GOFF + o] = g;
            }
        }
    }
}

extern "C" void kernel_launch(void* const* d_in, const int* in_sizes, int n_in,
                              void* d_out, int out_size, void* d_ws, size_t ws_size,
                              hipStream_t stream) {
    const float* x       = (const float*)d_in[0];
    const float* W       = (const float*)d_in[1];
    const float* bias    = (const float*)d_in[2];
    const float* contrib = (const float*)d_in[3];
    float* out = (float*)d_out;

    dim3 grid(M_TOT / BM);   // 1024 blocks
    dim3 block(512);
    dn_fused<<<grid, block, 0, stream>>>(x, W, bias, contrib, out);
}

// Round 2
// 213.867 us; speedup vs baseline: 1.0798x; 1.0798x over previous
//
#include <hip/hip_runtime.h>
#include <hip/hip_bf16.h>

typedef __attribute__((ext_vector_type(8))) short bf16x8;
typedef __attribute__((ext_vector_type(4))) float f32x4;

#define B_SZ   1024
#define T_SZ   128
#define L_SZ   256
#define F_SZ   784
#define M_TOT  (B_SZ * T_SZ)            // 131072
#define BM     128
#define BK     32
#define KSTEPS 25                       // ceil(784/32), tail zero-padded

#define WPRE_ELEMS (KSTEPS * 4 * L_SZ)  // 25600 bf16x8 elements
#define WPRE_BYTES (WPRE_ELEMS * 16)    // 409600
#define CDIFF_ELEMS (T_SZ * L_SZ)       // 32768
#define WS_NEED (WPRE_BYTES + CDIFF_ELEMS * 4)

__device__ __forceinline__ unsigned short f2bf(float f) {
    __hip_bfloat16 h = __float2bfloat16(f);   // RTNE
    return *reinterpret_cast<unsigned short*>(&h);
}

#define GLD16(g, l)                                                          \
    __builtin_amdgcn_global_load_lds(                                        \
        (const __attribute__((address_space(1))) void*)(g),                  \
        (__attribute__((address_space(3))) void*)(l), 16, 0, 0)

// ---------------- prep: W -> bf16 LDS-image layout; cdiff = c0 - c1 --------
__global__ __launch_bounds__(256) void dn_prep(
    const float* __restrict__ W, const float* __restrict__ contrib,
    unsigned short* __restrict__ wpre, float* __restrict__ cdiff)
{
    const int gid = blockIdx.x * 256 + threadIdx.x;
    if (gid < WPRE_ELEMS) {
        // wpre[ks][kgrp][leaf] : bf16x8 = W[leaf][ks*32+kgrp*8 .. +8), 0-padded
        const int leaf = gid & 255;
        const int kg   = (gid >> 8) & 3;
        const int ks   = gid >> 10;
        const int k0   = ks * BK + kg * 8;
        bf16x8 v;
        #pragma unroll
        for (int j = 0; j < 8; ++j) {
            const int k = k0 + j;
            const float f = (k < F_SZ) ? W[(size_t)leaf * F_SZ + k] : 0.f;
            v[j] = (short)f2bf(f);
        }
        *reinterpret_cast<bf16x8*>(wpre + (size_t)gid * 8) = v;
    } else {
        const int cid = gid - WPRE_ELEMS;
        if (cid < CDIFF_ELEMS)
            cdiff[cid] = contrib[(size_t)cid * 2] - contrib[(size_t)cid * 2 + 1];
    }
}

// ---------------- main fused kernel (v2: dbuf LDS, 1 barrier/iter) ---------
__global__ __launch_bounds__(512) void dn_fused2(
    const float* __restrict__ x, const unsigned short* __restrict__ wpre,
    const float* __restrict__ bias, const float* __restrict__ cdiff,
    float* __restrict__ out)
{
    __shared__ bf16x8 As[2][4][BM];     // 2 x 8KB
    __shared__ bf16x8 Bs[2][4][L_SZ];   // 2 x 16KB

    const int tid    = threadIdx.x;
    const int lane   = tid & 63;
    const int wid    = tid >> 6;
    const int waveM  = wid >> 2;
    const int waveN  = wid & 3;
    const int blkRow = blockIdx.x * BM;

    const int ar = tid >> 2;            // x row in tile (4 thr/row)
    const int ak = (tid & 3) * 8;       // x k offset 0/8/16/24

    const int laneRow = lane & 15;
    const int kgrp    = lane >> 4;

    f32x4 acc[4][4];
    #pragma unroll
    for (int i = 0; i < 4; ++i)
        #pragma unroll
        for (int j = 0; j < 4; ++j)
            acc[i][j] = (f32x4){0.f, 0.f, 0.f, 0.f};

    const float* xrow = x + (size_t)(blkRow + ar) * F_SZ;
    const f32x4  zf   = {0.f, 0.f, 0.f, 0.f};
    f32x4 xa0, xa1;

    // x-tile load into regs (tile p); tail (k>=784) zero-filled
    auto loadx = [&](int p) {
        const int kb = p * BK;
        if (kb + ak < F_SZ) {
            xa0 = *reinterpret_cast<const f32x4*>(xrow + kb + ak);
            xa1 = *reinterpret_cast<const f32x4*>(xrow + kb + ak + 4);
        } else { xa0 = zf; xa1 = zf; }
    };
    // cvt staged x regs -> LDS buf b
    auto cvtA = [&](int b) {
        bf16x8 av;
        #pragma unroll
        for (int j = 0; j < 4; ++j) {
            av[j]     = (short)f2bf(xa0[j]);
            av[4 + j] = (short)f2bf(xa1[j]);
        }
        As[b][ak >> 3][ar] = av;
    };
    // async stage Bs buf b <- wpre tile p (16KB, 2 x 1KB per wave)
    auto stageB = [&](int b, int p) {
        const char* g = (const char*)wpre + (size_t)p * 16384 + wid * 2048 + lane * 16;
        char*       l = ((char*)&Bs[b][0][0]) + wid * 2048;
        GLD16(g, l);
        GLD16(g + 1024, l + 1024);
    };

    // prologue: fill buf0 with tile 0, prefetch x tile 1
    loadx(0);
    cvtA(0);
    stageB(0, 0);
    loadx(1);
    __syncthreads();

    for (int k = 0; k < KSTEPS; ++k) {
        const int cur = k & 1, nxt = cur ^ 1;
        if (k + 1 < KSTEPS) {
            cvtA(nxt);                 // x tile k+1 (regs from prev iter)
            stageB(nxt, k + 1);        // async W tile k+1
            if (k + 2 < KSTEPS) loadx(k + 2);
        }

        bf16x8 af[4], bfv[4];
        #pragma unroll
        for (int mi = 0; mi < 4; ++mi)
            af[mi] = As[cur][kgrp][waveM * 64 + mi * 16 + laneRow];
        #pragma unroll
        for (int ni = 0; ni < 4; ++ni)
            bfv[ni] = Bs[cur][kgrp][waveN * 64 + ni * 16 + laneRow];

        __builtin_amdgcn_s_setprio(1);
        #pragma unroll
        for (int mi = 0; mi < 4; ++mi)
            #pragma unroll
            for (int ni = 0; ni < 4; ++ni)
                acc[mi][ni] = __builtin_amdgcn_mfma_f32_16x16x32_bf16(
                    af[mi], bfv[ni], acc[mi][ni], 0, 0, 0);
        __builtin_amdgcn_s_setprio(0);
        __syncthreads();
    }

    // epilogue: sp = clip(acc + b); gini = 1 + 2 s (1-s), s = sigmoid(sp * cdiff)
    const size_t GOFF  = (size_t)M_TOT * L_SZ;
    const int    rbase = waveM * 64 + (lane >> 4) * 4;
    const int    cbase = waveN * 64 + laneRow;
    #pragma unroll
    for (int ni = 0; ni < 4; ++ni) {
        const int col = cbase + ni * 16;
        const float bb = bias[col];
        #pragma unroll
        for (int mi = 0; mi < 4; ++mi) {
            #pragma unroll
            for (int r = 0; r < 4; ++r) {
                const int m = blkRow + rbase + mi * 16 + r;
                const int t = m & (T_SZ - 1);
                float v  = acc[mi][ni][r] + bb;
                float sp = fminf(fmaxf(v, -1.f), 1.f);
                const float d  = sp * cdiff[t * L_SZ + col];
                const float ed = __expf(d);
                const float s  = ed / (1.f + ed);
                const float g  = fmaf(2.f * s, 1.f - s, 1.f);
                const size_t o = (size_t)m * L_SZ + col;
                out[o]        = sp;
                out[GOFF + o] = g;
            }
        }
    }
}

// ---------------- v1 fallback (no workspace needed) ------------------------
__global__ __launch_bounds__(512) void dn_fused_v1(
    const float* __restrict__ x, const float* __restrict__ W,
    const float* __restrict__ bias, const float* __restrict__ contrib,
    float* __restrict__ out)
{
    __shared__ bf16x8 As[4][BM];
    __shared__ bf16x8 Bs[4][L_SZ];

    const int tid    = threadIdx.x;
    const int lane   = tid & 63;
    const int wid    = tid >> 6;
    const int waveM  = wid >> 2;
    const int waveN  = wid & 3;
    const int blkRow = blockIdx.x * BM;
    const int ar = tid >> 2;
    const int ak = (tid & 3) * 8;
    const int wr = tid >> 1;
    const int wk = (tid & 1) * 16;
    const int laneRow = lane & 15;
    const int kgrp    = lane >> 4;

    f32x4 acc[4][4];
    #pragma unroll
    for (int i = 0; i < 4; ++i)
        #pragma unroll
        for (int j = 0; j < 4; ++j)
            acc[i][j] = (f32x4){0.f, 0.f, 0.f, 0.f};

    const float* xrow = x + (size_t)(blkRow + ar) * F_SZ;
    const float* wrow = W + (size_t)wr * F_SZ;
    const f32x4 zf = {0.f, 0.f, 0.f, 0.f};

    f32x4 xa0 = *reinterpret_cast<const f32x4*>(xrow + ak);
    f32x4 xa1 = *reinterpret_cast<const f32x4*>(xrow + ak + 4);
    f32x4 wa0 = *reinterpret_cast<const f32x4*>(wrow + wk);
    f32x4 wa1 = *reinterpret_cast<const f32x4*>(wrow + wk + 4);
    f32x4 wa2 = *reinterpret_cast<const f32x4*>(wrow + wk + 8);
    f32x4 wa3 = *reinterpret_cast<const f32x4*>(wrow + wk + 12);

    for (int ks = 0; ks < KSTEPS; ++ks) {
        bf16x8 av, wv0, wv1;
        #pragma unroll
        for (int j = 0; j < 4; ++j) {
            av[j]      = (short)f2bf(xa0[j]);
            av[4 + j]  = (short)f2bf(xa1[j]);
            wv0[j]     = (short)f2bf(wa0[j]);
            wv0[4 + j] = (short)f2bf(wa1[j]);
            wv1[j]     = (short)f2bf(wa2[j]);
            wv1[4 + j] = (short)f2bf(wa3[j]);
        }
        As[ak >> 3][ar] = av;
        Bs[wk >> 3][wr] = wv0;
        Bs[(wk >> 3) + 1][wr] = wv1;
        __syncthreads();

        if (ks + 1 < KSTEPS) {
            const int kb = (ks + 1) * BK;
            if (kb + ak < F_SZ) {
                xa0 = *reinterpret_cast<const f32x4*>(xrow + kb + ak);
                xa1 = *reinterpret_cast<const f32x4*>(xrow + kb + ak + 4);
            } else { xa0 = zf; xa1 = zf; }
            if (kb + wk < F_SZ) {
                wa0 = *reinterpret_cast<const f32x4*>(wrow + kb + wk);
                wa1 = *reinterpret_cast<const f32x4*>(wrow + kb + wk + 4);
                wa2 = *reinterpret_cast<const f32x4*>(wrow + kb + wk + 8);
                wa3 = *reinterpret_cast<const f32x4*>(wrow + kb + wk + 12);
            } else { wa0 = zf; wa1 = zf; wa2 = zf; wa3 = zf; }
        }

        bf16x8 af[4], bfv[4];
        #pragma unroll
        for (int mi = 0; mi < 4; ++mi)
            af[mi] = As[kgrp][waveM * 64 + mi * 16 + laneRow];
        #pragma unroll
        for (int ni = 0; ni < 4; ++ni)
            bfv[ni] = Bs[kgrp][waveN * 64 + ni * 16 + laneRow];
        #pragma unroll
        for (int mi = 0; mi < 4; ++mi)
            #pragma unroll
            for (int ni = 0; ni < 4; ++ni)
                acc[mi][ni] = __builtin_amdgcn_mfma_f32_16x16x32_bf16(
                    af[mi], bfv[ni], acc[mi][ni], 0, 0, 0);
        __syncthreads();
    }

    const size_t GOFF  = (size_t)M_TOT * L_SZ;
    const int    rbase = waveM * 64 + (lane >> 4) * 4;
    const int    cbase = waveN * 64 + laneRow;
    #pragma unroll
    for (int ni = 0; ni < 4; ++ni) {
        const int col = cbase + ni * 16;
        const float bb = bias[col];
        #pragma unroll
        for (int mi = 0; mi < 4; ++mi) {
            #pragma unroll
            for (int r = 0; r < 4; ++r) {
                const int m = blkRow + rbase + mi * 16 + r;
                const int t = m & (T_SZ - 1);
                float v  = acc[mi][ni][r] + bb;
                float sp = fminf(fmaxf(v, -1.f), 1.f);
                const float* cp = contrib + (size_t)(t * L_SZ + col) * 2;
                const float d  = sp * (cp[0] - cp[1]);
                const float ed = __expf(d);
                const float s  = ed / (1.f + ed);
                const float g  = fmaf(2.f * s, 1.f - s, 1.f);
                const size_t o = (size_t)m * L_SZ + col;
                out[o]        = sp;
                out[GOFF + o] = g;
            }
        }
    }
}

extern "C" void kernel_launch(void* const* d_in, const int* in_sizes, int n_in,
                              void* d_out, int out_size, void* d_ws, size_t ws_size,
                              hipStream_t stream) {
    const float* x       = (const float*)d_in[0];
    const float* W       = (const float*)d_in[1];
    const float* bias    = (const float*)d_in[2];
    const float* contrib = (const float*)d_in[3];
    float* out = (float*)d_out;

    if (ws_size >= (size_t)WS_NEED && d_ws != nullptr) {
        unsigned short* wpre  = (unsigned short*)d_ws;
        float*          cdiff = (float*)((char*)d_ws + WPRE_BYTES);
        const int prep_threads = WPRE_ELEMS + CDIFF_ELEMS;
        dn_prep<<<(prep_threads + 255) / 256, 256, 0, stream>>>(W, contrib, wpre, cdiff);
        dn_fused2<<<M_TOT / BM, 512, 0, stream>>>(x, wpre, bias, cdiff, out);
    } else {
        dn_fused_v1<<<M_TOT / BM, 512, 0, stream>>>(x, W, bias, contrib, out);
    }
}